// Round 9
// baseline (215.782 us; speedup 1.0000x reference)
//
#include <hip/hip_runtime.h>

// MFMA fragment types
typedef short bf16x8 __attribute__((ext_vector_type(8)));
typedef float f32x16 __attribute__((ext_vector_type(16)));

__device__ __forceinline__ unsigned short f2bf(float f) {
    union { float f; unsigned int u; } v; v.f = f;
    unsigned int r = v.u + 0x7fffu + ((v.u >> 16) & 1u);  // RNE, inputs never NaN
    return (unsigned short)(r >> 16);
}

__device__ __forceinline__ unsigned int pack_bf16(float a, float b) {
#if __has_builtin(__builtin_amdgcn_cvt_pk_bf16_f32)
    typedef __bf16 bf16x2 __attribute__((ext_vector_type(2)));
    bf16x2 p = __builtin_amdgcn_cvt_pk_bf16_f32(a, b);
    union { bf16x2 v; unsigned int u; } c; c.v = p;
    return c.u;
#else
    return (unsigned int)f2bf(a) | ((unsigned int)f2bf(b) << 16);
#endif
}

__device__ __forceinline__ float fast_sigmoid8(float x) {
    // sigmoid(x/8) = 1/(1+2^(x * -0.125*log2(e)))
    float e = __builtin_exp2f(x * -0.180336880f);
    return __builtin_amdgcn_rcpf(1.0f + e);
}

// ---------------------------------------------------------------------------
// prep (height stage): per (b, bx=w) block: slab[k=h][c] = feature[b,h,w,c],
//   Q -> Qg [b][4096][64] bf16 row-major ; V -> Vtg [b][64][4096] bf16 (T)
// ---------------------------------------------------------------------------
__global__ __launch_bounds__(256) void prep_kernel(
    const float* __restrict__ src,
    const float* __restrict__ wq, const float* __restrict__ bq,
    const float* __restrict__ wv, const float* __restrict__ bv,
    unsigned short* __restrict__ Qg, unsigned short* __restrict__ Vtg)
{
    __shared__ float slab[64][65];
    __shared__ float wqs[4096];
    __shared__ float wvs[4096];

    const int t  = threadIdx.x;
    const int bx = blockIdx.x, b = blockIdx.y;

    {   // stage weights
        const float4* wq4 = (const float4*)wq;
        const float4* wv4 = (const float4*)wv;
        float4* q4 = (float4*)wqs; float4* v4 = (float4*)wvs;
        #pragma unroll
        for (int i = 0; i < 4; ++i) {
            q4[i*256 + t] = wq4[i*256 + t];
            v4[i*256 + t] = wv4[i*256 + t];
        }
    }
    {   // stage slab: k=h rows (stride 4096), bx=w fixed
        const int k = t >> 2, c0 = (t & 3) << 4;
        const size_t sb = (size_t)b*262144 + (size_t)k*4096 + (size_t)bx*64 + c0;
        #pragma unroll
        for (int i = 0; i < 4; ++i)
            *(float4*)&slab[k][c0 + i*4] = *(const float4*)&src[sb + i*4];
    }
    __syncthreads();

    const int c = t & 63, jg = t >> 6;
    float qa[16], va[16];
    #pragma unroll
    for (int jj = 0; jj < 16; ++jj) { qa[jj] = bq[jg*16+jj]; va[jj] = bv[jg*16+jj]; }
    for (int k = 0; k < 64; ++k) {
        const float xv = slab[k][c];
        const float* wqr = &wqs[k*64 + jg*16];
        const float* wvr = &wvs[k*64 + jg*16];
        #pragma unroll
        for (int jj = 0; jj < 16; ++jj) {
            qa[jj] += xv * wqr[jj];
            va[jj] += xv * wvr[jj];
        }
    }
    const int token = bx*64 + c;
    union { unsigned short s[16]; uint4 v[2]; } qp, vp;
    #pragma unroll
    for (int jj = 0; jj < 16; ++jj) { qp.s[jj] = f2bf(qa[jj]); vp.s[jj] = f2bf(va[jj]); }
    const size_t qoff = ((size_t)b*4096 + token)*64 + jg*16;
    *(uint4*)&Qg[qoff]     = qp.v[0];
    *(uint4*)&Qg[qoff + 8] = qp.v[1];
    #pragma unroll
    for (int jj = 0; jj < 16; ++jj)
        Vtg[((size_t)b*64 + jg*16 + jj)*4096 + token] = vp.s[jj];
}

// ---------------------------------------------------------------------------
// prep_w (width stage) FUSED with fold_h:
//   x1 = feature + g*sum_ks(P_h) computed during slab staging, then Q/V GEMM.
// ---------------------------------------------------------------------------
__global__ __launch_bounds__(256) void prep_w_kernel(
    const float* __restrict__ feature, const float* __restrict__ Pin,
    const float* __restrict__ gate,
    const float* __restrict__ wq, const float* __restrict__ bq,
    const float* __restrict__ wv, const float* __restrict__ bv,
    unsigned short* __restrict__ Qg, unsigned short* __restrict__ Vtg,
    float* __restrict__ x1out, int nsplit)
{
    __shared__ float slab[64][65];
    __shared__ float wqs[4096];
    __shared__ float wvs[4096];

    const int t  = threadIdx.x;
    const int bx = blockIdx.x, b = blockIdx.y;   // bx = h

    {   // stage weights
        const float4* wq4 = (const float4*)wq;
        const float4* wv4 = (const float4*)wv;
        float4* q4 = (float4*)wqs; float4* v4 = (float4*)wvs;
        #pragma unroll
        for (int i = 0; i < 4; ++i) {
            q4[i*256 + t] = wq4[i*256 + t];
            v4[i*256 + t] = wv4[i*256 + t];
        }
    }
    {   // stage slab with inline fold: P_h[ks][b][d=h][token=w*64+c]
        const int k = t >> 2, c0 = (t & 3) << 4;
        const size_t off = (size_t)bx*4096 + (size_t)k*64 + c0;  // h*4096 + w*64 + c
        const size_t fb  = (size_t)b*262144 + off;
        const float g = gate[0];
        #pragma unroll
        for (int i = 0; i < 4; ++i) {
            float4 v  = *(const float4*)&feature[fb + i*4];
            float sx = 0.f, sy = 0.f, sz = 0.f, sw = 0.f;
            for (int ks = 0; ks < nsplit; ++ks) {
                float4 pk = *(const float4*)&Pin[((size_t)(ks*4 + b) << 18) + off + i*4];
                sx += pk.x; sy += pk.y; sz += pk.z; sw += pk.w;
            }
            v.x += g * sx; v.y += g * sy; v.z += g * sz; v.w += g * sw;
            *(float4*)&slab[k][c0 + i*4] = v;
            *(float4*)&x1out[fb + i*4] = v;
        }
    }
    __syncthreads();

    const int c = t & 63, jg = t >> 6;
    float qa[16], va[16];
    #pragma unroll
    for (int jj = 0; jj < 16; ++jj) { qa[jj] = bq[jg*16+jj]; va[jj] = bv[jg*16+jj]; }
    for (int k = 0; k < 64; ++k) {
        const float xv = slab[k][c];
        const float* wqr = &wqs[k*64 + jg*16];
        const float* wvr = &wvs[k*64 + jg*16];
        #pragma unroll
        for (int jj = 0; jj < 16; ++jj) {
            qa[jj] += xv * wqr[jj];
            va[jj] += xv * wvr[jj];
        }
    }
    const int token = bx*64 + c;
    union { unsigned short s[16]; uint4 v[2]; } qp, vp;
    #pragma unroll
    for (int jj = 0; jj < 16; ++jj) { qp.s[jj] = f2bf(qa[jj]); vp.s[jj] = f2bf(va[jj]); }
    const size_t qoff = ((size_t)b*4096 + token)*64 + jg*16;
    *(uint4*)&Qg[qoff]     = qp.v[0];
    *(uint4*)&Qg[qoff + 8] = qp.v[1];
    #pragma unroll
    for (int jj = 0; jj < 16; ++jj)
        Vtg[((size_t)b*64 + jg*16 + jj)*4096 + token] = vp.s[jj];
}

// ---------------------------------------------------------------------------
// attn v9 = r8 core (32x32x16 MFMA, single-buffer staging, reg prefetch,
// 2 barriers/iter, wave-private Ss) with ksplit taken from gridDim.z.
// Each block: 128 queries, 4096/gridDim.z keys in 64-key tiles.
// Epilogue: plain partial stores P[ksplit][b][d][token].
// ---------------------------------------------------------------------------
__global__ __launch_bounds__(256) void attn_kernel(
    const unsigned short* __restrict__ Qg,
    const unsigned short* __restrict__ Vtg,
    float* __restrict__ P)
{
    __shared__ unsigned short Ksh[64][72];
    __shared__ unsigned short Vts[64][72];
    __shared__ unsigned short Ss[128][72];   // rows wave-private (w*32+l32)

    const int t = threadIdx.x;
    const int mb = blockIdx.x, b = blockIdx.y, ksplit = blockIdx.z;
    const int nsp = gridDim.z;
    const int niter = 64 / nsp;              // 64-key tiles per block
    const int keybase = ksplit * (4096 / nsp);
    const int lane = t & 63, w = t >> 6;
    const int l32 = lane & 31, hi = lane >> 5;

    const unsigned short* Qbase = Qg  + (size_t)b*262144;
    const unsigned short* Vbase = Vtg + (size_t)b*262144;

    // Q B-frags: n=query=l32, k=d = s*16 + hi*8 + j
    bf16x8 qb[4];
    {
        const unsigned short* qrow = Qbase + (size_t)(mb*128 + w*32 + l32)*64 + hi*8;
        qb[0] = *(const bf16x8*)(qrow);
        qb[1] = *(const bf16x8*)(qrow + 16);
        qb[2] = *(const bf16x8*)(qrow + 32);
        qb[3] = *(const bf16x8*)(qrow + 48);
    }

    f32x16 y[2];
    #pragma unroll
    for (int i = 0; i < 16; ++i) { y[0][i] = 0.f; y[1][i] = 0.f; }

    const int lrow = t >> 2;
    const int loff = (t & 3) << 4;   // shorts
    {   // prologue: stage tile 0
        const uint4* gk = (const uint4*)(Qbase + (size_t)(keybase + lrow)*64 + loff);
        uint4 k0 = gk[0], k1 = gk[1];
        const uint4* gv = (const uint4*)(Vbase + (size_t)lrow*4096 + keybase + loff);
        uint4 v0 = gv[0], v1 = gv[1];
        *(uint4*)&Ksh[lrow][loff]     = k0;
        *(uint4*)&Ksh[lrow][loff + 8] = k1;
        *(uint4*)&Vts[lrow][loff]     = v0;
        *(uint4*)&Vts[lrow][loff + 8] = v1;
    }
    __syncthreads();

    unsigned short* srowS = &Ss[w*32 + l32][0];
    unsigned int*   srowU = (unsigned int*)srowS;

    for (int kb = 0; kb < niter; ++kb) {
        // prefetch next tile into registers (in flight across compute phase)
        uint4 nk0 = {0,0,0,0}, nk1 = {0,0,0,0}, nv0 = {0,0,0,0}, nv1 = {0,0,0,0};
        if (kb < niter - 1) {
            const int keyn = keybase + (kb + 1)*64;
            const uint4* gk = (const uint4*)(Qbase + (size_t)(keyn + lrow)*64 + loff);
            nk0 = gk[0]; nk1 = gk[1];
            const uint4* gv = (const uint4*)(Vbase + (size_t)lrow*4096 + keyn + loff);
            nv0 = gv[0]; nv1 = gv[1];
        }

        // T = K·Q^T : tt[u] covers keys u*32..+32 for this wave's 32 queries
        f32x16 tt[2];
        #pragma unroll
        for (int i = 0; i < 16; ++i) { tt[0][i] = 0.f; tt[1][i] = 0.f; }
        #pragma unroll
        for (int s = 0; s < 4; ++s) {
            const int co = s*16 + hi*8;
            bf16x8 ka0 = *(const bf16x8*)&Ksh[l32][co];
            bf16x8 ka1 = *(const bf16x8*)&Ksh[32 + l32][co];
            tt[0] = __builtin_amdgcn_mfma_f32_32x32x16_bf16(ka0, qb[s], tt[0], 0,0,0);
            tt[1] = __builtin_amdgcn_mfma_f32_32x32x16_bf16(ka1, qb[s], tt[1], 0,0,0);
        }

        // sigmoid + pack: lane holds T[key=u*32+8g+4hi+e][query=l32], e=0..3
        #pragma unroll
        for (int u = 0; u < 2; ++u)
            #pragma unroll
            for (int g = 0; g < 4; ++g) {
                uint2 pk;
                pk.x = pack_bf16(fast_sigmoid8(tt[u][4*g+0]), fast_sigmoid8(tt[u][4*g+1]));
                pk.y = pack_bf16(fast_sigmoid8(tt[u][4*g+2]), fast_sigmoid8(tt[u][4*g+3]));
                *(uint2*)&srowU[u*16 + g*4 + hi*2] = pk;
            }
        // wave-private rows: in-wave lgkmcnt ordering, no barrier for round-trip

        // Y += S·V : A = S[q=l32][key], B[k=key][n=d] from Vt rows
        #pragma unroll
        for (int ks = 0; ks < 4; ++ks) {
            const int co = ks*16 + hi*8;
            bf16x8 sa  = *(const bf16x8*)&srowS[co];
            bf16x8 vb0 = *(const bf16x8*)&Vts[l32][co];
            bf16x8 vb1 = *(const bf16x8*)&Vts[32 + l32][co];
            y[0] = __builtin_amdgcn_mfma_f32_32x32x16_bf16(sa, vb0, y[0], 0,0,0);
            y[1] = __builtin_amdgcn_mfma_f32_32x32x16_bf16(sa, vb1, y[1], 0,0,0);
        }

        __syncthreads();   // all waves done reading current tile
        if (kb < niter - 1) {
            *(uint4*)&Ksh[lrow][loff]     = nk0;
            *(uint4*)&Ksh[lrow][loff + 8] = nk1;
            *(uint4*)&Vts[lrow][loff]     = nv0;
            *(uint4*)&Vts[lrow][loff + 8] = nv1;
        }
        __syncthreads();   // next tile visible
    }

    // epilogue: P[ksplit][b][d][token]; token = mb*128 + w*32 + 8g + 4hi + e
    float* Pp = P + (((size_t)(ksplit*4 + b)) << 18);
    const int token0 = mb*128 + w*32 + hi*4;
    #pragma unroll
    for (int dt = 0; dt < 2; ++dt) {
        const int d = dt*32 + l32;
        #pragma unroll
        for (int g = 0; g < 4; ++g) {
            float4 v;
            v.x = y[dt][4*g+0]; v.y = y[dt][4*g+1];
            v.z = y[dt][4*g+2]; v.w = y[dt][4*g+3];
            *(float4*)&Pp[(size_t)d*4096 + token0 + 8*g] = v;
        }
    }
}

// ---------------------------------------------------------------------------
// final: out = p * (feature + x1 + g*sum_ks P_w[ks][b][d=w][token=h*64+c])
// ---------------------------------------------------------------------------
__global__ __launch_bounds__(256) void final_kernel(
    const float* __restrict__ feature, const float* __restrict__ x1,
    const float* __restrict__ Pin, const float* __restrict__ predict,
    const float* __restrict__ conv_w, const float* __restrict__ conv_b,
    const float* __restrict__ gate, float* __restrict__ out, int nsplit)
{
    const int i4 = blockIdx.x * 256 + threadIdx.x;   // [0, 262144)
    const int j = i4 << 2;
    const int pix = j >> 6;
    const float* row = predict + (size_t)pix * 19;
    float pv = conv_b[0];
    #pragma unroll
    for (int i = 0; i < 19; ++i) {
        float sg = __builtin_amdgcn_rcpf(1.0f + __builtin_exp2f(-1.442695041f * row[i]));
        pv += (1.0f - sg) * conv_w[i];
    }

    const int b = j >> 18, h = (j >> 12) & 63, d = (j >> 6) & 63, c = j & 63;
    const size_t pif = ((size_t)(b*64 + d) << 12) + h*64 + c;
    float sx = 0.f, sy = 0.f, sz = 0.f, sw = 0.f;
    for (int ks = 0; ks < nsplit; ++ks) {
        float4 pk = *(const float4*)&Pin[((size_t)ks << 20) + pif];
        sx += pk.x; sy += pk.y; sz += pk.z; sw += pk.w;
    }
    const float g = gate[0];
    float4 f = ((const float4*)feature)[i4];
    float4 x = ((const float4*)x1)[i4];
    float4 o;
    o.x = pv * (f.x + x.x + g * sx);
    o.y = pv * (f.y + x.y + g * sy);
    o.z = pv * (f.z + x.z + g * sz);
    o.w = pv * (f.w + x.w + g * sw);
    ((float4*)out)[i4] = o;
}

extern "C" void kernel_launch(void* const* d_in, const int* in_sizes, int n_in,
                              void* d_out, int out_size, void* d_ws, size_t ws_size,
                              hipStream_t stream) {
    const float* feature = (const float*)d_in[0];
    const float* predict = (const float*)d_in[1];
    const float* hq_w = (const float*)d_in[2];
    const float* hq_b = (const float*)d_in[3];
    const float* hv_w = (const float*)d_in[4];
    const float* hv_b = (const float*)d_in[5];
    const float* wq_w = (const float*)d_in[6];
    const float* wq_b = (const float*)d_in[7];
    const float* wv_w = (const float*)d_in[8];
    const float* wv_b = (const float*)d_in[9];
    const float* h_gate = (const float*)d_in[10];
    const float* w_gate = (const float*)d_in[11];
    const float* conv_w = (const float*)d_in[12];
    const float* conv_b = (const float*)d_in[13];
    float* out = (float*)d_out;

    // workspace: Qg 2MB | Vtg 2MB | x1 4MB | P nsplit*4MB
    char* ws = (char*)d_ws;
    unsigned short* Qg  = (unsigned short*)(ws);
    unsigned short* Vtg = (unsigned short*)(ws + (2u << 20));
    float*          x1  = (float*)(ws + (4u << 20));
    float*          P   = (float*)(ws + (8u << 20));
    // nsplit=8 needs 8+32=40 MiB; fall back to 4 (24 MiB, r7/r8-proven) if short
    const int nsplit = (ws_size >= (40u << 20)) ? 8 : 4;

    dim3 blk(256);
    // height stage
    prep_kernel<<<dim3(64, 4), blk, 0, stream>>>(feature, hq_w, hq_b, hv_w, hv_b,
                                                 Qg, Vtg);
    attn_kernel<<<dim3(32, 4, nsplit), blk, 0, stream>>>(Qg, Vtg, P);
    // width stage: x1 = feature + h_gate*sum(P) computed inline
    prep_w_kernel<<<dim3(64, 4), blk, 0, stream>>>(feature, P, h_gate,
                                                   wq_w, wq_b, wv_w, wv_b,
                                                   Qg, Vtg, x1, nsplit);
    attn_kernel<<<dim3(32, 4, nsplit), blk, 0, stream>>>(Qg, Vtg, P);
    // out = p * (feature + x1 + w_gate*sum(P))
    final_kernel<<<dim3(1024), blk, 0, stream>>>(feature, x1, P, predict,
                                                 conv_w, conv_b, w_gate, out, nsplit);
}

// Round 11
// 189.178 us; speedup vs baseline: 1.1406x; 1.1406x over previous
//
#include <hip/hip_runtime.h>

// MFMA fragment types (f16 flavor)
typedef _Float16 f16x8 __attribute__((ext_vector_type(8)));
typedef __fp16   fp16x2 __attribute__((ext_vector_type(2)));
typedef float f32x16 __attribute__((ext_vector_type(16)));

__device__ __forceinline__ unsigned pkrtz(float a, float b) {
    fp16x2 h = __builtin_amdgcn_cvt_pkrtz(a, b);   // src0->low, src1->high
    union { fp16x2 h; unsigned u; } c; c.h = h; return c.u;
}

__device__ __forceinline__ unsigned short f2h(float f) {
    _Float16 h = (_Float16)f;
    union { _Float16 h; unsigned short s; } c; c.h = h; return c.s;
}

// sigmoid((q·k)/8) with the -0.125*log2e scale pre-folded into Q:
// s = 1 / (1 + 2^t) where t = K·Qscaled
__device__ __forceinline__ float sig_from_t(float t) {
    return __builtin_amdgcn_rcpf(1.0f + __builtin_exp2f(t));
}

// ---------------------------------------------------------------------------
// prep (height stage): per (b, bx=w) block: slab[k=h][c] = feature[b,h,w,c],
//   Q -> Qg [b][4096][64] f16 row-major ; V -> Vtg [b][64][4096] f16 (T)
// ---------------------------------------------------------------------------
__global__ __launch_bounds__(256) void prep_kernel(
    const float* __restrict__ src,
    const float* __restrict__ wq, const float* __restrict__ bq,
    const float* __restrict__ wv, const float* __restrict__ bv,
    unsigned short* __restrict__ Qg, unsigned short* __restrict__ Vtg)
{
    __shared__ float slab[64][65];
    __shared__ float wqs[4096];
    __shared__ float wvs[4096];

    const int t  = threadIdx.x;
    const int bx = blockIdx.x, b = blockIdx.y;

    {   // stage weights
        const float4* wq4 = (const float4*)wq;
        const float4* wv4 = (const float4*)wv;
        float4* q4 = (float4*)wqs; float4* v4 = (float4*)wvs;
        #pragma unroll
        for (int i = 0; i < 4; ++i) {
            q4[i*256 + t] = wq4[i*256 + t];
            v4[i*256 + t] = wv4[i*256 + t];
        }
    }
    {   // stage slab: k=h rows (stride 4096), bx=w fixed
        const int k = t >> 2, c0 = (t & 3) << 4;
        const size_t sb = (size_t)b*262144 + (size_t)k*4096 + (size_t)bx*64 + c0;
        #pragma unroll
        for (int i = 0; i < 4; ++i)
            *(float4*)&slab[k][c0 + i*4] = *(const float4*)&src[sb + i*4];
    }
    __syncthreads();

    const int c = t & 63, jg = t >> 6;
    float qa[16], va[16];
    #pragma unroll
    for (int jj = 0; jj < 16; ++jj) { qa[jj] = bq[jg*16+jj]; va[jj] = bv[jg*16+jj]; }
    for (int k = 0; k < 64; ++k) {
        const float xv = slab[k][c];
        const float* wqr = &wqs[k*64 + jg*16];
        const float* wvr = &wvs[k*64 + jg*16];
        #pragma unroll
        for (int jj = 0; jj < 16; ++jj) {
            qa[jj] += xv * wqr[jj];
            va[jj] += xv * wvr[jj];
        }
    }
    const int token = bx*64 + c;
    union { unsigned u[8]; uint4 v[2]; } qp;
    #pragma unroll
    for (int jj = 0; jj < 8; ++jj) qp.u[jj] = pkrtz(qa[2*jj], qa[2*jj+1]);
    const size_t qoff = ((size_t)b*4096 + token)*64 + jg*16;
    *(uint4*)&Qg[qoff]     = qp.v[0];
    *(uint4*)&Qg[qoff + 8] = qp.v[1];
    #pragma unroll
    for (int jj = 0; jj < 16; ++jj)
        Vtg[((size_t)b*64 + jg*16 + jj)*4096 + token] = f2h(va[jj]);
}

// ---------------------------------------------------------------------------
// prep_w (width stage) FUSED with fold_h:
//   x1 = feature + g*sum_ks(P_h) computed during slab staging, then Q/V GEMM.
// ---------------------------------------------------------------------------
__global__ __launch_bounds__(256) void prep_w_kernel(
    const float* __restrict__ feature, const float* __restrict__ Pin,
    const float* __restrict__ gate,
    const float* __restrict__ wq, const float* __restrict__ bq,
    const float* __restrict__ wv, const float* __restrict__ bv,
    unsigned short* __restrict__ Qg, unsigned short* __restrict__ Vtg,
    float* __restrict__ x1out, int nsplit)
{
    __shared__ float slab[64][65];
    __shared__ float wqs[4096];
    __shared__ float wvs[4096];

    const int t  = threadIdx.x;
    const int bx = blockIdx.x, b = blockIdx.y;   // bx = h

    {   // stage weights
        const float4* wq4 = (const float4*)wq;
        const float4* wv4 = (const float4*)wv;
        float4* q4 = (float4*)wqs; float4* v4 = (float4*)wvs;
        #pragma unroll
        for (int i = 0; i < 4; ++i) {
            q4[i*256 + t] = wq4[i*256 + t];
            v4[i*256 + t] = wv4[i*256 + t];
        }
    }
    {   // stage slab with inline fold: P_h[ks][b][d=h][token=w*64+c]
        const int k = t >> 2, c0 = (t & 3) << 4;
        const size_t off = (size_t)bx*4096 + (size_t)k*64 + c0;  // h*4096 + w*64 + c
        const size_t fb  = (size_t)b*262144 + off;
        const float g = gate[0];
        #pragma unroll
        for (int i = 0; i < 4; ++i) {
            float4 v  = *(const float4*)&feature[fb + i*4];
            float sx = 0.f, sy = 0.f, sz = 0.f, sw = 0.f;
            for (int ks = 0; ks < nsplit; ++ks) {
                float4 pk = *(const float4*)&Pin[((size_t)(ks*4 + b) << 18) + off + i*4];
                sx += pk.x; sy += pk.y; sz += pk.z; sw += pk.w;
            }
            v.x += g * sx; v.y += g * sy; v.z += g * sz; v.w += g * sw;
            *(float4*)&slab[k][c0 + i*4] = v;
            *(float4*)&x1out[fb + i*4] = v;
        }
    }
    __syncthreads();

    const int c = t & 63, jg = t >> 6;
    float qa[16], va[16];
    #pragma unroll
    for (int jj = 0; jj < 16; ++jj) { qa[jj] = bq[jg*16+jj]; va[jj] = bv[jg*16+jj]; }
    for (int k = 0; k < 64; ++k) {
        const float xv = slab[k][c];
        const float* wqr = &wqs[k*64 + jg*16];
        const float* wvr = &wvs[k*64 + jg*16];
        #pragma unroll
        for (int jj = 0; jj < 16; ++jj) {
            qa[jj] += xv * wqr[jj];
            va[jj] += xv * wvr[jj];
        }
    }
    const int token = bx*64 + c;
    union { unsigned u[8]; uint4 v[2]; } qp;
    #pragma unroll
    for (int jj = 0; jj < 8; ++jj) qp.u[jj] = pkrtz(qa[2*jj], qa[2*jj+1]);
    const size_t qoff = ((size_t)b*4096 + token)*64 + jg*16;
    *(uint4*)&Qg[qoff]     = qp.v[0];
    *(uint4*)&Qg[qoff + 8] = qp.v[1];
    #pragma unroll
    for (int jj = 0; jj < 16; ++jj)
        Vtg[((size_t)b*64 + jg*16 + jj)*4096 + token] = f2h(va[jj]);
}

// ---------------------------------------------------------------------------
// attn v10: f16 MFMA 32x32x16; sigmoid scale folded into Q frags; S transpose
// done IN REGISTERS via __shfl_xor(·,32) (no Ss LDS, no S round-trip).
// C-layout (m74/m101): col(query)=lane&31, key=(reg&3)+8*(reg>>2)+4*(lane>>5).
// A-frag for S·V (16-key step ks): lane needs keys ks*16+hi*8+j:
//   w0 = hi?x(Qa):Pa ; w1 = hi?x(Qb):Pb ; w2 = hi?Qa:x(Pa) ; w3 = hi?Qb:x(Pb)
// where Pa..Qb are packed pairs of this lane's regs, x() = shfl_xor 32.
// Single-buffer K/V staging, reg prefetch, 2 barriers/iter.
// ---------------------------------------------------------------------------
__global__ __launch_bounds__(256) void attn_kernel(
    const unsigned short* __restrict__ Qg,
    const unsigned short* __restrict__ Vtg,
    float* __restrict__ P)
{
    __shared__ unsigned short Ksh[64][72];
    __shared__ unsigned short Vts[64][72];

    const int t = threadIdx.x;
    const int mb = blockIdx.x, b = blockIdx.y, ksplit = blockIdx.z;
    const int nsp = gridDim.z;
    const int niter = 64 / nsp;
    const int keybase = ksplit * (4096 / nsp);
    const int lane = t & 63, w = t >> 6;
    const int l32 = lane & 31, hi = lane >> 5;

    const unsigned short* Qbase = Qg  + (size_t)b*262144;
    const unsigned short* Vbase = Vtg + (size_t)b*262144;

    // Q B-frags (n=query=l32, k=d=s*16+hi*8+j), scaled by -0.125*log2(e)
    f16x8 qb[4];
    {
        const unsigned short* qrow = Qbase + (size_t)(mb*128 + w*32 + l32)*64 + hi*8;
        const _Float16 sc = (_Float16)(-0.180336880f);
        #pragma unroll
        for (int s = 0; s < 4; ++s) {
            f16x8 q = *(const f16x8*)(qrow + s*16);
            qb[s] = q * sc;
        }
    }

    f32x16 y[2];
    #pragma unroll
    for (int i = 0; i < 16; ++i) { y[0][i] = 0.f; y[1][i] = 0.f; }

    const int lrow = t >> 2;
    const int loff = (t & 3) << 4;
    {   // prologue: stage tile 0
        const uint4* gk = (const uint4*)(Qbase + (size_t)(keybase + lrow)*64 + loff);
        uint4 k0 = gk[0], k1 = gk[1];
        const uint4* gv = (const uint4*)(Vbase + (size_t)lrow*4096 + keybase + loff);
        uint4 v0 = gv[0], v1 = gv[1];
        *(uint4*)&Ksh[lrow][loff]     = k0;
        *(uint4*)&Ksh[lrow][loff + 8] = k1;
        *(uint4*)&Vts[lrow][loff]     = v0;
        *(uint4*)&Vts[lrow][loff + 8] = v1;
    }
    __syncthreads();

    for (int kb = 0; kb < niter; ++kb) {
        // prefetch next tile into registers
        uint4 nk0 = {0,0,0,0}, nk1 = {0,0,0,0}, nv0 = {0,0,0,0}, nv1 = {0,0,0,0};
        if (kb < niter - 1) {
            const int keyn = keybase + (kb + 1)*64;
            const uint4* gk = (const uint4*)(Qbase + (size_t)(keyn + lrow)*64 + loff);
            nk0 = gk[0]; nk1 = gk[1];
            const uint4* gv = (const uint4*)(Vbase + (size_t)lrow*4096 + keyn + loff);
            nv0 = gv[0]; nv1 = gv[1];
        }

        // T = K·Qs^T : tt[u] covers keys u*32..+32 (scale pre-folded)
        f32x16 tt[2];
        #pragma unroll
        for (int i = 0; i < 16; ++i) { tt[0][i] = 0.f; tt[1][i] = 0.f; }
        #pragma unroll
        for (int s = 0; s < 4; ++s) {
            const int co = s*16 + hi*8;
            f16x8 ka0 = *(const f16x8*)&Ksh[l32][co];
            f16x8 ka1 = *(const f16x8*)&Ksh[32 + l32][co];
            tt[0] = __builtin_amdgcn_mfma_f32_32x32x16_f16(ka0, qb[s], tt[0], 0,0,0);
            tt[1] = __builtin_amdgcn_mfma_f32_32x32x16_f16(ka1, qb[s], tt[1], 0,0,0);
        }

        // per 32-key tile: sigmoid -> pack -> cross-half swap -> S·V MFMA
        #pragma unroll
        for (int u = 0; u < 2; ++u) {
            float sg[16];
            #pragma unroll
            for (int r = 0; r < 16; ++r) sg[r] = sig_from_t(tt[u][r]);
            #pragma unroll
            for (int ksh = 0; ksh < 2; ++ksh) {
                const int bR = ksh*8;
                unsigned Pa = pkrtz(sg[bR+0], sg[bR+1]);
                unsigned Pb = pkrtz(sg[bR+2], sg[bR+3]);
                unsigned Qa = pkrtz(sg[bR+4], sg[bR+5]);
                unsigned Qb = pkrtz(sg[bR+6], sg[bR+7]);
                unsigned xPa = __shfl_xor(Pa, 32);
                unsigned xPb = __shfl_xor(Pb, 32);
                unsigned xQa = __shfl_xor(Qa, 32);
                unsigned xQb = __shfl_xor(Qb, 32);
                union { unsigned u[4]; f16x8 v; } sa;
                sa.u[0] = hi ? xQa : Pa;
                sa.u[1] = hi ? xQb : Pb;
                sa.u[2] = hi ? Qa : xPa;
                sa.u[3] = hi ? Qb : xPb;

                const int ks = u*2 + ksh;           // absolute 16-key step
                const int co = ks*16 + hi*8;
                f16x8 vb0 = *(const f16x8*)&Vts[l32][co];
                f16x8 vb1 = *(const f16x8*)&Vts[32 + l32][co];
                y[0] = __builtin_amdgcn_mfma_f32_32x32x16_f16(sa.v, vb0, y[0], 0,0,0);
                y[1] = __builtin_amdgcn_mfma_f32_32x32x16_f16(sa.v, vb1, y[1], 0,0,0);
            }
        }

        __syncthreads();   // all waves done reading current tile
        if (kb < niter - 1) {
            *(uint4*)&Ksh[lrow][loff]     = nk0;
            *(uint4*)&Ksh[lrow][loff + 8] = nk1;
            *(uint4*)&Vts[lrow][loff]     = nv0;
            *(uint4*)&Vts[lrow][loff + 8] = nv1;
        }
        __syncthreads();   // next tile visible
    }

    // epilogue: P[ksplit][b][d][token]; token = mb*128 + w*32 + 8g + 4hi + e
    float* Pp = P + (((size_t)(ksplit*4 + b)) << 18);
    const int token0 = mb*128 + w*32 + hi*4;
    #pragma unroll
    for (int dt = 0; dt < 2; ++dt) {
        const int d = dt*32 + l32;
        #pragma unroll
        for (int g = 0; g < 4; ++g) {
            float4 v;
            v.x = y[dt][4*g+0]; v.y = y[dt][4*g+1];
            v.z = y[dt][4*g+2]; v.w = y[dt][4*g+3];
            *(float4*)&Pp[(size_t)d*4096 + token0 + 8*g] = v;
        }
    }
}

// ---------------------------------------------------------------------------
// final: out = p * (feature + x1 + g*sum_ks P_w[ks][b][d=w][token=h*64+c])
// ---------------------------------------------------------------------------
__global__ __launch_bounds__(256) void final_kernel(
    const float* __restrict__ feature, const float* __restrict__ x1,
    const float* __restrict__ Pin, const float* __restrict__ predict,
    const float* __restrict__ conv_w, const float* __restrict__ conv_b,
    const float* __restrict__ gate, float* __restrict__ out, int nsplit)
{
    const int i4 = blockIdx.x * 256 + threadIdx.x;   // [0, 262144)
    const int j = i4 << 2;
    const int pix = j >> 6;
    const float* row = predict + (size_t)pix * 19;
    float pv = conv_b[0];
    #pragma unroll
    for (int i = 0; i < 19; ++i) {
        float sg = __builtin_amdgcn_rcpf(1.0f + __builtin_exp2f(-1.442695041f * row[i]));
        pv += (1.0f - sg) * conv_w[i];
    }

    const int b = j >> 18, h = (j >> 12) & 63, d = (j >> 6) & 63, c = j & 63;
    const size_t pif = ((size_t)(b*64 + d) << 12) + h*64 + c;
    float sx = 0.f, sy = 0.f, sz = 0.f, sw = 0.f;
    for (int ks = 0; ks < nsplit; ++ks) {
        float4 pk = *(const float4*)&Pin[((size_t)ks << 20) + pif];
        sx += pk.x; sy += pk.y; sz += pk.z; sw += pk.w;
    }
    const float g = gate[0];
    float4 f = ((const float4*)feature)[i4];
    float4 x = ((const float4*)x1)[i4];
    float4 o;
    o.x = pv * (f.x + x.x + g * sx);
    o.y = pv * (f.y + x.y + g * sy);
    o.z = pv * (f.z + x.z + g * sz);
    o.w = pv * (f.w + x.w + g * sw);
    ((float4*)out)[i4] = o;
}

extern "C" void kernel_launch(void* const* d_in, const int* in_sizes, int n_in,
                              void* d_out, int out_size, void* d_ws, size_t ws_size,
                              hipStream_t stream) {
    const float* feature = (const float*)d_in[0];
    const float* predict = (const float*)d_in[1];
    const float* hq_w = (const float*)d_in[2];
    const float* hq_b = (const float*)d_in[3];
    const float* hv_w = (const float*)d_in[4];
    const float* hv_b = (const float*)d_in[5];
    const float* wq_w = (const float*)d_in[6];
    const float* wq_b = (const float*)d_in[7];
    const float* wv_w = (const float*)d_in[8];
    const float* wv_b = (const float*)d_in[9];
    const float* h_gate = (const float*)d_in[10];
    const float* w_gate = (const float*)d_in[11];
    const float* conv_w = (const float*)d_in[12];
    const float* conv_b = (const float*)d_in[13];
    float* out = (float*)d_out;

    // workspace: Qg 2MB | Vtg 2MB | x1 4MB | P nsplit*4MB (nsplit=4 -> 24 MiB)
    char* ws = (char*)d_ws;
    unsigned short* Qg  = (unsigned short*)(ws);
    unsigned short* Vtg = (unsigned short*)(ws + (2u << 20));
    float*          x1  = (float*)(ws + (4u << 20));
    float*          P   = (float*)(ws + (8u << 20));
    const int nsplit = 4;   // r9: nsplit=8 bought nothing in attn, cost ~12us in folds

    dim3 blk(256);
    // height stage
    prep_kernel<<<dim3(64, 4), blk, 0, stream>>>(feature, hq_w, hq_b, hv_w, hv_b,
                                                 Qg, Vtg);
    attn_kernel<<<dim3(32, 4, nsplit), blk, 0, stream>>>(Qg, Vtg, P);
    // width stage: x1 = feature + h_gate*sum(P) computed inline
    prep_w_kernel<<<dim3(64, 4), blk, 0, stream>>>(feature, P, h_gate,
                                                   wq_w, wq_b, wv_w, wv_b,
                                                   Qg, Vtg, x1, nsplit);
    attn_kernel<<<dim3(32, 4, nsplit), blk, 0, stream>>>(Qg, Vtg, P);
    // out = p * (feature + x1 + w_gate*sum(P))
    final_kernel<<<dim3(1024), blk, 0, stream>>>(feature, x1, P, predict,
                                                 conv_w, conv_b, w_gate, out, nsplit);
}